// Round 1
// baseline (682.555 us; speedup 1.0000x reference)
//
#include <hip/hip_runtime.h>
#include <math.h>

// ---------------------------------------------------------------------------
// Kernel 1: int4 symmetric per-tensor weight quantization (Brevitas-style).
//   scale = max|W| / 7 ;  Wq = clip(rint(W/scale), -8, 7) * scale
// Writes Wq TRANSPOSED into wqt as [2048][4] floats so the main kernel can
// fetch all 4 output-channels' weights for a feature with one float4 load.
// 1 block x 1024 threads, float4 loads: 2048 float4 = whole W in 2 rounds.
// Must run every launch: d_ws is re-poisoned before each timed call.
// ---------------------------------------------------------------------------
__global__ __launch_bounds__(1024) void quant_w_kernel(
        const float* __restrict__ W, float* __restrict__ wqt /* [2048][4] */) {
    __shared__ float smax[16];
    __shared__ float sscale;
    const int t = threadIdx.x;                       // 0..1023
    const float4 v0 = ((const float4*)W)[t];         // floats 4t .. 4t+3
    const float4 v1 = ((const float4*)W)[t + 1024];  // floats 4t+4096 ..

    float m = fmaxf(
        fmaxf(fmaxf(fabsf(v0.x), fabsf(v0.y)), fmaxf(fabsf(v0.z), fabsf(v0.w))),
        fmaxf(fmaxf(fabsf(v1.x), fabsf(v1.y)), fmaxf(fabsf(v1.z), fabsf(v1.w))));
    #pragma unroll
    for (int off = 32; off; off >>= 1) m = fmaxf(m, __shfl_xor(m, off));
    if ((t & 63) == 0) smax[t >> 6] = m;
    __syncthreads();
    if (t == 0) {
        float M = smax[0];
        #pragma unroll
        for (int i = 1; i < 16; ++i) M = fmaxf(M, smax[i]);
        sscale = M / 7.0f;
    }
    __syncthreads();
    const float scale = sscale;

    // quantize + transposed scatter store (8192 scalar stores total: tiny)
#define QSTORE(val, idx)                                              \
    {                                                                 \
        const int i_ = (idx);                                         \
        const int o_ = i_ >> 11;          /* output channel 0..3 */   \
        const int f_ = i_ & 2047;         /* feature */               \
        float q_ = rintf((val) / scale);  /* half-to-even like np */  \
        q_ = fminf(fmaxf(q_, -8.0f), 7.0f);                           \
        wqt[f_ * 4 + o_] = q_ * scale;                                \
    }
    const int i0 = t << 2;
    QSTORE(v0.x, i0 + 0); QSTORE(v0.y, i0 + 1);
    QSTORE(v0.z, i0 + 2); QSTORE(v0.w, i0 + 3);
    QSTORE(v1.x, i0 + 4096); QSTORE(v1.y, i0 + 4097);
    QSTORE(v1.z, i0 + 4098); QSTORE(v1.w, i0 + 4099);
#undef QSTORE
}

// ---------------------------------------------------------------------------
// Kernel 2: fused maxpool(2^3) + linear(2048->4) + bias + softmax.
// ONE WAVE per batch item (4 waves / 256-thread block, grid = 2048 blocks).
// No LDS, no __syncthreads. Per iteration the wave reads 4 KB fully
// contiguous = 4 complete d-planes (16 B per lane, dense):
//   lane l -> 16B quarter-row: h = l>>2, w-quarter q = l&3, of each plane.
// Pooling: w-pairs inside the float4 (x,y | z,w), d-pairs across the two
// plane registers, h-pairs via __shfl_xor(lane^4). The two d-pairs of the
// 4-plane group are split across even-h / odd-h lanes so every lane owns
// 2 unique pooled features -> 2 float4 weight FMAs. Zero redundancy.
// Feature id: f = c*512 + dp*64 + hp*8 + wp  ==  it*128 + hodd*64 + hp*8 + 2q.
// ---------------------------------------------------------------------------
__global__ __launch_bounds__(256) void fused_pool_linear_softmax(
        const float* __restrict__ x,     // [8192][4][16][16][16]
        const float* __restrict__ wqt,   // [2048][4]
        const float* __restrict__ bias,  // [4]
        float* __restrict__ out) {       // [8192][4]
    const int t  = threadIdx.x;
    const int wv = t >> 6;                       // wave in block: 0..3
    const int l  = t & 63;                       // lane
    const int b  = (blockIdx.x << 2) + wv;       // batch item

    const float* __restrict__ p = x + (size_t)b * 16384 + (l << 2);
    const int hodd = (l >> 2) & 1;               // h parity
    const int f0   = hodd * 64 + (l >> 3) * 8 + ((l & 3) << 1);
    const float* __restrict__ wp = wqt + f0 * 4;

    float4 acc = make_float4(0.f, 0.f, 0.f, 0.f);

    #pragma unroll 4
    for (int it = 0; it < 16; ++it) {
        // 4 consecutive d-planes, 1 KB each, wave-dense
        const float4 v0 = *(const float4*)(p);        // plane d+0 (chunk A)
        const float4 v1 = *(const float4*)(p + 256);  // plane d+1 (chunk A)
        const float4 v2 = *(const float4*)(p + 512);  // plane d+2 (chunk B)
        const float4 v3 = *(const float4*)(p + 768);  // plane d+3 (chunk B)
        p += 1024;

        // w-pair + d-pair pooling in-register
        const float aA = fmaxf(fmaxf(v0.x, v0.y), fmaxf(v1.x, v1.y)); // wp=2q
        const float bA = fmaxf(fmaxf(v0.z, v0.w), fmaxf(v1.z, v1.w)); // wp=2q+1
        const float aB = fmaxf(fmaxf(v2.x, v2.y), fmaxf(v3.x, v3.y));
        const float bB = fmaxf(fmaxf(v2.z, v2.w), fmaxf(v3.z, v3.w));

        // h-pair pooling with the lane^4 partner
        const float saA = __shfl_xor(aA, 4);
        const float sbA = __shfl_xor(bA, 4);
        const float saB = __shfl_xor(aB, 4);
        const float sbB = __shfl_xor(bB, 4);

        const float p0 = hodd ? fmaxf(aB, saB) : fmaxf(aA, saA);
        const float p1 = hodd ? fmaxf(bB, sbB) : fmaxf(bA, sbA);

        const float4 w0 = *(const float4*)(wp);       // channels for f0
        const float4 w1 = *(const float4*)(wp + 4);   // channels for f0+1
        wp += 512;                                    // +128 features / iter

        acc.x = fmaf(p0, w0.x, fmaf(p1, w1.x, acc.x));
        acc.y = fmaf(p0, w0.y, fmaf(p1, w1.y, acc.y));
        acc.z = fmaf(p0, w0.z, fmaf(p1, w1.z, acc.z));
        acc.w = fmaf(p0, w0.w, fmaf(p1, w1.w, acc.w));
    }

    // in-wave butterfly: all 64 lanes hold disjoint feature partial sums
    #pragma unroll
    for (int off = 32; off; off >>= 1) {
        acc.x += __shfl_xor(acc.x, off);
        acc.y += __shfl_xor(acc.y, off);
        acc.z += __shfl_xor(acc.z, off);
        acc.w += __shfl_xor(acc.w, off);
    }

    if (l == 0) {
        const float4 bi = *(const float4*)bias;
        const float l0 = acc.x + bi.x, l1 = acc.y + bi.y,
                    l2 = acc.z + bi.z, l3 = acc.w + bi.w;
        const float m  = fmaxf(fmaxf(l0, l1), fmaxf(l2, l3));
        const float e0 = expf(l0 - m), e1 = expf(l1 - m),
                    e2 = expf(l2 - m), e3 = expf(l3 - m);
        const float inv = 1.0f / (e0 + e1 + e2 + e3);
        *(float4*)(out + (size_t)b * 4) =
            make_float4(e0 * inv, e1 * inv, e2 * inv, e3 * inv);
    }
}

extern "C" void kernel_launch(void* const* d_in, const int* in_sizes, int n_in,
                              void* d_out, int out_size, void* d_ws, size_t ws_size,
                              hipStream_t stream) {
    const float* x    = (const float*)d_in[0];   // [8192,4,16,16,16]
    const float* W    = (const float*)d_in[1];   // [4,2048]
    const float* bias = (const float*)d_in[2];   // [4]
    float* out = (float*)d_out;                  // [8192,4]
    float* wqt = (float*)d_ws;                   // [2048][4] quantized W^T

    quant_w_kernel<<<1, 1024, 0, stream>>>(W, wqt);
    fused_pool_linear_softmax<<<2048, 256, 0, stream>>>(x, wqt, bias, out);
}